// Round 8
// baseline (590.031 us; speedup 1.0000x reference)
//
#include <hip/hip_runtime.h>
#include <hip/hip_bf16.h>

#define B_ 4
#define S_ 2048
#define D_ 1024
#define H_ 16
#define TSZ 8388608L  // B*S*D elements

typedef short short8 __attribute__((ext_vector_type(8)));
typedef float f32x4 __attribute__((ext_vector_type(4)));

__device__ inline unsigned short f2b(float f) {
  __hip_bfloat16 h = __float2bfloat16(f);
  return __builtin_bit_cast(unsigned short, h);
}
// async global->LDS, 16 bytes per lane; LDS dest must be wave-uniform base
__device__ inline void gld16(const unsigned short* g, unsigned short* l) {
  __builtin_amdgcn_global_load_lds(
      (const __attribute__((address_space(1))) void*)g,
      (__attribute__((address_space(3))) void*)l, 16, 0, 0);
}

// ---------------- mask pack: int32 (B,S,S) -> bitmask ----------------------
// word index = ((row*16 + kt)*4 + g), bit (W*4+r) = mask[row][kt*128+W*16+g*4+r]
__global__ __launch_bounds__(256) void mask_pack(const int* __restrict__ mask,
                                                 unsigned int* __restrict__ mp) {
  long t = (long)blockIdx.x * 256 + threadIdx.x;  // t = row*16 + kt
  const int4* p = (const int4*)(mask + (t >> 4) * (long)S_ + (t & 15) * 128);
  unsigned int w0 = 0, w1 = 0, w2 = 0, w3 = 0;
#pragma unroll
  for (int c = 0; c < 32; c++) {
    int4 v = p[c];
#pragma unroll
    for (int e = 0; e < 4; e++) {
      int k = c * 4 + e;
      int val = e == 0 ? v.x : e == 1 ? v.y : e == 2 ? v.z : v.w;
      int nb = k >> 4, p16 = k & 15;
      int gg = p16 >> 2, r = p16 & 3;
      unsigned bit = ((unsigned)val & 1u) << (nb * 4 + r);
      if (gg == 0) w0 |= bit; else if (gg == 1) w1 |= bit;
      else if (gg == 2) w2 |= bit; else w3 |= bit;
    }
  }
  *(uint4*)(mp + t * 4) = make_uint4(w0, w1, w2, w3);
}

// ---------------- f32 -> bf16 convert for Q,K,V (one launch) ---------------
__global__ __launch_bounds__(256) void cvt3(
    const float* __restrict__ Q, const float* __restrict__ K,
    const float* __restrict__ V, unsigned short* __restrict__ qo,
    unsigned short* __restrict__ ko, unsigned short* __restrict__ vo) {
  int seg = blockIdx.x >> 12;
  long i = ((long)(blockIdx.x & 4095) * 256 + threadIdx.x) * 8;
  const float* in = seg == 0 ? Q : seg == 1 ? K : V;
  unsigned short* out = seg == 0 ? qo : seg == 1 ? ko : vo;
  float4 a = *(const float4*)(in + i);
  float4 b = *(const float4*)(in + i + 4);
  short8 u;
  u[0] = (short)f2b(a.x); u[1] = (short)f2b(a.y);
  u[2] = (short)f2b(a.z); u[3] = (short)f2b(a.w);
  u[4] = (short)f2b(b.x); u[5] = (short)f2b(b.y);
  u[6] = (short)f2b(b.z); u[7] = (short)f2b(b.w);
  *(short8*)(out + i) = u;
}

// ---------------- weight transpose x4: W f32 [K][N] -> Wt bf16 [N][K] ------
__global__ __launch_bounds__(256) void transpose_w4(
    const float* __restrict__ W0, const float* __restrict__ W1,
    const float* __restrict__ W2, const float* __restrict__ W3,
    unsigned short* __restrict__ T0, unsigned short* __restrict__ T1,
    unsigned short* __restrict__ T2, unsigned short* __restrict__ T3) {
  __shared__ unsigned short t[64 * 72];  // [k][n] pitch 72
  const int z = blockIdx.z;
  const float* W = z == 0 ? W0 : z == 1 ? W1 : z == 2 ? W2 : W3;
  unsigned short* Wt = z == 0 ? T0 : z == 1 ? T1 : z == 2 ? T2 : T3;
  const int tid = threadIdx.x;
  const int k0 = blockIdx.x * 64, n0 = blockIdx.y * 64;
#pragma unroll
  for (int p = 0; p < 4; p++) {
    int e = (p * 256 + tid) * 4;
    int r = e >> 6, c = e & 63;
    float4 v = *(const float4*)(W + (long)(k0 + r) * D_ + n0 + c);
    ushort4 u;
    u.x = f2b(v.x); u.y = f2b(v.y); u.z = f2b(v.z); u.w = f2b(v.w);
    *(ushort4*)(&t[r * 72 + c]) = u;
  }
  __syncthreads();
#pragma unroll
  for (int p = 0; p < 2; p++) {
    int e = (p * 256 + tid) * 8;
    int n = e >> 6, kc = e & 63;
    short8 x;
#pragma unroll
    for (int i = 0; i < 8; i++) x[i] = (short)t[(kc + i) * 72 + n];
    *(short8*)(Wt + (long)(n0 + n) * D_ + k0 + kc) = x;
  }
}

// ---------------- fused QKV projection GEMM --------------------------------
// z=0: Q->qh (head-major), z=1: K->kh (head-major), z=2: V->vt (transposed,
// sigma-permuted within 32-key chunks + row-XOR swizzle for attn LDS)
__global__ __launch_bounds__(256) void qkv_gemm(
    const unsigned short* __restrict__ qa, const unsigned short* __restrict__ ka,
    const unsigned short* __restrict__ va, const unsigned short* __restrict__ wq,
    const unsigned short* __restrict__ wk, const unsigned short* __restrict__ wv,
    const float* __restrict__ bqp, const float* __restrict__ bkp,
    const float* __restrict__ bvp, unsigned short* __restrict__ qo,
    unsigned short* __restrict__ ko, unsigned short* __restrict__ vo) {
  __shared__ unsigned short Asm[128 * 32];
  __shared__ unsigned short Bsm[128 * 32];
  const int z = blockIdx.z;
  const unsigned short* A = z == 0 ? qa : z == 1 ? ka : va;
  const unsigned short* Wt = z == 0 ? wq : z == 1 ? wk : wv;
  const float* bias = z == 0 ? bqp : z == 1 ? bkp : bvp;
  unsigned short* outp = z == 0 ? qo : z == 1 ? ko : vo;
  const int tid = threadIdx.x;
  const int lane = tid & 63, wid = tid >> 6;
  const int g = lane >> 4, li = lane & 15;
  const int wm = wid >> 1, wn = wid & 1;
  const long bm = (long)blockIdx.x * 128;
  const long bn = (long)blockIdx.y * 128;

  f32x4 acc[4][4];
#pragma unroll
  for (int i = 0; i < 4; i++)
#pragma unroll
    for (int j = 0; j < 4; j++) acc[i][j] = (f32x4){0.f, 0.f, 0.f, 0.f};

  for (int kt = 0; kt < 32; ++kt) {
    const int k0 = kt * 32;
    __syncthreads();
#pragma unroll
    for (int p = 0; p < 2; p++) {
      int ci = p * 256 + wid * 64 + lane;
      int r = ci >> 2, c = (ci & 3) * 8;
      gld16(A + (bm + r) * 1024L + k0 + c, &Asm[(p * 256 + wid * 64) * 8]);
      gld16(Wt + (bn + r) * 1024L + k0 + c, &Bsm[(p * 256 + wid * 64) * 8]);
    }
    __syncthreads();
    short8 af[4], bf[4];
#pragma unroll
    for (int i = 0; i < 4; i++)
      af[i] = *(const short8*)(&Asm[(wm * 64 + i * 16 + li) * 32 + g * 8]);
#pragma unroll
    for (int i = 0; i < 4; i++)
      bf[i] = *(const short8*)(&Bsm[(wn * 64 + i * 16 + li) * 32 + g * 8]);
#pragma unroll
    for (int i = 0; i < 4; i++)
#pragma unroll
      for (int j = 0; j < 4; j++)
        acc[i][j] =
            __builtin_amdgcn_mfma_f32_16x16x32_bf16(af[i], bf[j], acc[i][j], 0, 0, 0);
  }

#pragma unroll
  for (int i = 0; i < 4; i++) {
    int row0 = (int)bm + wm * 64 + i * 16 + g * 4;
#pragma unroll
    for (int j = 0; j < 4; j++) {
      int col = (int)bn + wn * 64 + j * 16 + li;
      float bvv = bias[col];
      if (z == 2) {
        int b = row0 >> 11, s0 = row0 & 2047;
        int h = col >> 6, dd = col & 63;
        ushort4 u;
#pragma unroll
        for (int jj = 0; jj < 4; jj++) u[jj] = f2b(acc[i][j][jj] + bvv);
        // sigma permute within 32-key chunk, then row-XOR swizzle
        int kh2 = s0 & 31;
        int s1 = (s0 & ~31) | (((kh2 >> 2) & 3) << 3) | (((kh2 >> 4) & 1) << 2);
        int s2 = s1 ^ ((dd & 7) << 3);
        *(ushort4*)(outp + ((long)(b * H_ + h) * 64 + dd) * S_ + s2) = u;
      } else {
#pragma unroll
        for (int jj = 0; jj < 4; jj++) {
          int row = row0 + jj;
          int b = row >> 11, s = row & 2047;
          int h = col >> 6, dd = col & 63;
          outp[(((long)(b * H_ + h)) * S_ + s) * 64 + dd] =
              f2b(acc[i][j][jj] + bvv);
        }
      }
    }
  }
}

// ---------------- output GEMM: out = ctx @ Wo^T + bo (f32 out) -------------
__global__ __launch_bounds__(256) void wo_gemm(
    const unsigned short* __restrict__ A, const unsigned short* __restrict__ Wt,
    const float* __restrict__ bias, float* __restrict__ out) {
  __shared__ unsigned short Asm[128 * 32];
  __shared__ unsigned short Bsm[128 * 32];
  const int tid = threadIdx.x;
  const int lane = tid & 63, wid = tid >> 6;
  const int g = lane >> 4, li = lane & 15;
  const int wm = wid >> 1, wn = wid & 1;
  const long bm = (long)blockIdx.x * 128;
  const long bn = (long)blockIdx.y * 128;

  f32x4 acc[4][4];
#pragma unroll
  for (int i = 0; i < 4; i++)
#pragma unroll
    for (int j = 0; j < 4; j++) acc[i][j] = (f32x4){0.f, 0.f, 0.f, 0.f};

  for (int kt = 0; kt < 32; ++kt) {
    const int k0 = kt * 32;
    __syncthreads();
#pragma unroll
    for (int p = 0; p < 2; p++) {
      int ci = p * 256 + wid * 64 + lane;
      int r = ci >> 2, c = (ci & 3) * 8;
      gld16(A + (bm + r) * 1024L + k0 + c, &Asm[(p * 256 + wid * 64) * 8]);
      gld16(Wt + (bn + r) * 1024L + k0 + c, &Bsm[(p * 256 + wid * 64) * 8]);
    }
    __syncthreads();
    short8 af[4], bf[4];
#pragma unroll
    for (int i = 0; i < 4; i++)
      af[i] = *(const short8*)(&Asm[(wm * 64 + i * 16 + li) * 32 + g * 8]);
#pragma unroll
    for (int i = 0; i < 4; i++)
      bf[i] = *(const short8*)(&Bsm[(wn * 64 + i * 16 + li) * 32 + g * 8]);
#pragma unroll
    for (int i = 0; i < 4; i++)
#pragma unroll
      for (int j = 0; j < 4; j++)
        acc[i][j] =
            __builtin_amdgcn_mfma_f32_16x16x32_bf16(af[i], bf[j], acc[i][j], 0, 0, 0);
  }

#pragma unroll
  for (int i = 0; i < 4; i++) {
    int row0 = (int)bm + wm * 64 + i * 16 + g * 4;
#pragma unroll
    for (int j = 0; j < 4; j++) {
      int col = (int)bn + wn * 64 + j * 16 + li;
      float bvv = bias[col];
#pragma unroll
      for (int jj = 0; jj < 4; jj++)
        out[(long)(row0 + jj) * 1024 + col] = acc[i][j][jj] + bvv;
    }
  }
}

// ---------------- fused attn: key-split waves, K direct, V gld16-dbuf ------
#define LOADK(dst, kt)                                          \
  {                                                             \
    const unsigned short* _kp = kfbase + (long)(kt) * 8192;     \
    dst[0] = *(const short8*)_kp;                               \
    dst[1] = *(const short8*)(_kp + 32);                        \
    dst[2] = *(const short8*)(_kp + 1024);                      \
    dst[3] = *(const short8*)(_kp + 1056);                      \
  }

__global__ __launch_bounds__(256) void attn_kernel(
    const unsigned short* __restrict__ q,    // (BH,S,64)
    const unsigned short* __restrict__ k,    // (BH,S,64) plain
    const unsigned short* __restrict__ vt,   // (BH,64,S) sigma+XOR swizzled
    const unsigned int* __restrict__ mpk,    // packed mask
    float* __restrict__ attn,                // (BH,S,S) f32
    unsigned short* __restrict__ ctx) {      // (B,S,D) bf16
  __shared__ unsigned short v_lds[2][64 * 128];  // double-buffered V tile
  __shared__ float lred[4][32];
  const int tid = threadIdx.x;
  const int lane = tid & 63, w = tid >> 6;
  const int g = lane >> 4, li = lane & 15;
  // XCD-cluster swizzle (bijective): 8 heads per XCD
  const int p0 = blockIdx.x + 64 * blockIdx.y;
  const int xcd = p0 & 7, q8 = p0 >> 3;
  const int bx = q8 & 63, bh = xcd * 8 + (q8 >> 6);
  const int b = bh >> 4, h = bh & 15;
  const int qw = bx * 32;

  const unsigned short* qp = q + ((long)bh * S_ + qw) * 64;
  short8 aq0[2], aq1[2];
#pragma unroll
  for (int qb = 0; qb < 2; qb++) {
    aq0[qb] = *(const short8*)(qp + (qb * 16 + li) * 64 + g * 8);
    aq1[qb] = *(const short8*)(qp + (qb * 16 + li) * 64 + 32 + g * 8);
  }
  const unsigned short* kfbase =
      k + ((long)bh * S_ + w * 32 + li) * 64 + g * 8;
  const unsigned short* vbase = vt + (long)bh * 64 * S_;
  int vsrc[4];
#pragma unroll
  for (int p = 0; p < 4; p++) {
    int ci = p * 256 + tid;
    vsrc[p] = (ci >> 4) * S_ + (ci & 15) * 8;
  }
  // prologue: stage V tile 0 into buf0 (overlaps pass 1)
#pragma unroll
  for (int p = 0; p < 4; p++)
    gld16(vbase + vsrc[p], &v_lds[0][(p * 256 + w * 64) * 8]);

  const unsigned int* mpb0 = mpk + ((long)(b * S_ + qw + li) * 16) * 4 + g;
  const unsigned int* mpb1 = mpb0 + 1024;  // +16 rows

  // ---- pass 1: denominators (barrier-free, K direct + reg ping-pong) ----
  float ls0 = 0.f, ls1 = 0.f;
  short8 kA[4], kB[4];
  unsigned int mA0, mA1, mB0, mB1;
  LOADK(kA, 0);
  mA0 = mpb0[0]; mA1 = mpb1[0];
#define P1STEP(kt, KC, M0, M1, KN, MN0, MN1)                                  \
  {                                                                           \
    if ((kt) < 15) {                                                          \
      LOADK(KN, (kt) + 1);                                                    \
      MN0 = mpb0[((kt) + 1) * 4];                                             \
      MN1 = mpb1[((kt) + 1) * 4];                                             \
    }                                                                         \
    _Pragma("unroll") for (int nb = 0; nb < 2; nb++) {                        \
      f32x4 s0 = (f32x4){0.f, 0.f, 0.f, 0.f};                                 \
      f32x4 s1 = (f32x4){0.f, 0.f, 0.f, 0.f};                                 \
      __builtin_amdgcn_s_setprio(1);                                          \
      s0 = __builtin_amdgcn_mfma_f32_16x16x32_bf16(KC[nb * 2], aq0[0], s0, 0, 0, 0); \
      s0 = __builtin_amdgcn_mfma_f32_16x16x32_bf16(KC[nb * 2 + 1], aq1[0], s0, 0, 0, 0); \
      s1 = __builtin_amdgcn_mfma_f32_16x16x32_bf16(KC[nb * 2], aq0[1], s1, 0, 0, 0); \
      s1 = __builtin_amdgcn_mfma_f32_16x16x32_bf16(KC[nb * 2 + 1], aq1[1], s1, 0, 0, 0); \
      __builtin_amdgcn_s_setprio(0);                                          \
      _Pragma("unroll") for (int r = 0; r < 4; r++) {                         \
        int bi = (w * 2 + nb) * 4 + r;                                        \
        ls0 += __expf(s0[r] * 0.125f + (((M0 >> bi) & 1u) ? 0.f : -1e9f));    \
        ls1 += __expf(s1[r] * 0.125f + (((M1 >> bi) & 1u) ? 0.f : -1e9f));    \
      }                                                                       \
    }                                                                         \
  }
  for (int kt2 = 0; kt2 < 8; ++kt2) {
    P1STEP(2 * kt2, kA, mA0, mA1, kB, mB0, mB1);
    P1STEP(2 * kt2 + 1, kB, mB0, mB1, kA, mA0, mA1);
  }
  ls0 += __shfl_xor(ls0, 16); ls0 += __shfl_xor(ls0, 32);
  ls1 += __shfl_xor(ls1, 16); ls1 += __shfl_xor(ls1, 32);
  if (lane < 16) { lred[w][li] = ls0; lred[w][16 + li] = ls1; }
  __syncthreads();
  float t0 = lred[0][li] + lred[1][li] + lred[2][li] + lred[3][li];
  float t1 = lred[0][16 + li] + lred[1][16 + li] + lred[2][16 + li] +
             lred[3][16 + li];
  const float linv0 = (t0 > 0.f) ? 1.0f / t0 : 0.f;
  const float linv1 = (t1 > 0.f) ? 1.0f / t1 : 0.f;

  // ---- pass 2: probs + PV (1 barrier/kt, V dbuf) ----
  f32x4 c[2][4];
#pragma unroll
  for (int qb = 0; qb < 2; qb++)
#pragma unroll
    for (int d = 0; d < 4; d++) c[qb][d] = (f32x4){0.f, 0.f, 0.f, 0.f};
  LOADK(kA, 0);
  mA0 = mpb0[0]; mA1 = mpb1[0];
  float* arow0 = attn + ((long)bh * S_ + qw + li) * S_;
  const int vxor = (w * 32) ^ ((li & 7) << 3);
#define P2STEP(kt, buf, KC, M0, M1, KN, MN0, MN1)                             \
  {                                                                           \
    __syncthreads();                                                          \
    if ((kt) < 15) {                                                          \
      _Pragma("unroll") for (int p = 0; p < 4; p++)                           \
          gld16(vbase + ((kt) + 1) * 128 + vsrc[p],                           \
                &v_lds[(buf) ^ 1][(p * 256 + w * 64) * 8]);                   \
      LOADK(KN, (kt) + 1);                                                    \
      MN0 = mpb0[((kt) + 1) * 4];                                             \
      MN1 = mpb1[((kt) + 1) * 4];                                             \
    }                                                                         \
    short8 pu2[2];                                                            \
    _Pragma("unroll") for (int nb = 0; nb < 2; nb++) {                        \
      f32x4 s0 = (f32x4){0.f, 0.f, 0.f, 0.f};                                 \
      f32x4 s1 = (f32x4){0.f, 0.f, 0.f, 0.f};                                 \
      __builtin_amdgcn_s_setprio(1);                                          \
      s0 = __builtin_amdgcn_mfma_f32_16x16x32_bf16(KC[nb * 2], aq0[0], s0, 0, 0, 0); \
      s0 = __builtin_amdgcn_mfma_f32_16x16x32_bf16(KC[nb * 2 + 1], aq1[0], s0, 0, 0, 0); \
      s1 = __builtin_amdgcn_mfma_f32_16x16x32_bf16(KC[nb * 2], aq0[1], s1, 0, 0, 0); \
      s1 = __builtin_amdgcn_mfma_f32_16x16x32_bf16(KC[nb * 2 + 1], aq1[1], s1, 0, 0, 0); \
      __builtin_amdgcn_s_setprio(0);                                          \
      f32x4 pf0, pf1;                                                         \
      ushort4 pu0, pu1;                                                       \
      _Pragma("unroll") for (int r = 0; r < 4; r++) {                         \
        int bi = (w * 2 + nb) * 4 + r;                                        \
        float p0f = __expf(s0[r] * 0.125f + (((M0 >> bi) & 1u) ? 0.f : -1e9f)) * linv0; \
        float p1f = __expf(s1[r] * 0.125f + (((M1 >> bi) & 1u) ? 0.f : -1e9f)) * linv1; \
        pf0[r] = p0f; pu0[r] = f2b(p0f);                                      \
        pf1[r] = p1f; pu1[r] = f2b(p1f);                                      \
      }                                                                       \
      long acol = (kt) * 128 + (w * 2 + nb) * 16 + g * 4;                     \
      __builtin_nontemporal_store(pf0, (f32x4*)(arow0 + acol));               \
      __builtin_nontemporal_store(pf1, (f32x4*)(arow0 + 16 * S_ + acol));     \
      ((ushort4*)&pu2[0])[nb] = pu0;                                          \
      ((ushort4*)&pu2[1])[nb] = pu1;                                          \
    }                                                                         \
    __builtin_amdgcn_s_setprio(1);                                            \
    _Pragma("unroll") for (int d = 0; d < 4; d++) {                           \
      short8 bv = *(const short8*)(&v_lds[buf][(d * 16 + li) * 128 +          \
                                              (vxor ^ (g * 8))]);             \
      c[0][d] = __builtin_amdgcn_mfma_f32_16x16x32_bf16(pu2[0], bv, c[0][d], 0, 0, 0); \
      c[1][d] = __builtin_amdgcn_mfma_f32_16x16x32_bf16(pu2[1], bv, c[1][d], 0, 0, 0); \
    }                                                                         \
    __builtin_amdgcn_s_setprio(0);                                            \
  }
  for (int kt2 = 0; kt2 < 8; ++kt2) {
    P2STEP(2 * kt2, 0, kA, mA0, mA1, kB, mB0, mB1);
    P2STEP(2 * kt2 + 1, 1, kB, mB0, mB1, kA, mA0, mA1);
  }

  // ---- cross-wave ctx reduction ----
  __syncthreads();
  float* red = (float*)&v_lds[0][0];  // 8 KB
#pragma unroll
  for (int ph = 0; ph < 4; ++ph) {
    if (w == ph) {
#pragma unroll
      for (int qb = 0; qb < 2; qb++)
#pragma unroll
        for (int d = 0; d < 4; d++)
#pragma unroll
          for (int jj = 0; jj < 4; jj++) {
            int idx = (qb * 16 + g * 4 + jj) * 64 + d * 16 + li;
            red[idx] = (ph == 0 ? 0.f : red[idx]) + c[qb][d][jj];
          }
    }
    __syncthreads();
  }
  int row = tid >> 3, grp = tid & 7;
  const float* rp = red + row * 64 + grp * 8;
  short8 o;
#pragma unroll
  for (int j = 0; j < 8; j++) o[j] = (short)f2b(rp[j]);
  *(short8*)(ctx + ((long)(b * S_ + qw + row)) * D_ + h * 64 + grp * 8) = o;
}

extern "C" void kernel_launch(void* const* d_in, const int* in_sizes, int n_in,
                              void* d_out, int out_size, void* d_ws, size_t ws_size,
                              hipStream_t stream) {
  const float* Q = (const float*)d_in[0];
  const float* K = (const float*)d_in[1];
  const float* V = (const float*)d_in[2];
  const int* mask = (const int*)d_in[3];
  const float* Wq = (const float*)d_in[4];
  const float* bq = (const float*)d_in[5];
  const float* Wk = (const float*)d_in[6];
  const float* bk = (const float*)d_in[7];
  const float* Wv = (const float*)d_in[8];
  const float* bv = (const float*)d_in[9];
  const float* Wo = (const float*)d_in[10];
  const float* bo = (const float*)d_in[11];

  float* out = (float*)d_out;  // (B,S,D) f32
  float* attn = out + TSZ;     // (B,H,S,S) f32
  // packed mask (2 MB) lives in the out region; overwritten by final GEMM
  unsigned int* mpack = (unsigned int*)d_out;

  unsigned short* ws = (unsigned short*)d_ws;
  unsigned short* qh = ws;              // (BH,S,64) bf16
  unsigned short* kh = ws + TSZ;        // (BH,S,64)
  unsigned short* vt = ws + 2 * TSZ;    // (BH,64,S) swizzled
  unsigned short* ctx = ws + 3 * TSZ;   // (B,S,D) bf16
  unsigned short* qbf = ws + 4 * TSZ;   // bf16 inputs
  unsigned short* kbf = ws + 5 * TSZ;
  unsigned short* vbf = ws + 6 * TSZ;
  unsigned short* wtq = ws + 7 * TSZ;
  unsigned short* wtk = wtq + 1048576;
  unsigned short* wtv = wtk + 1048576;
  unsigned short* wto = wtv + 1048576;

  dim3 bb(256);
  mask_pack<<<512, bb, 0, stream>>>(mask, mpack);
  cvt3<<<12288, bb, 0, stream>>>(Q, K, V, qbf, kbf, vbf);
  transpose_w4<<<dim3(16, 16, 4), bb, 0, stream>>>(Wq, Wk, Wv, Wo, wtq, wtk,
                                                   wtv, wto);
  qkv_gemm<<<dim3(64, 8, 3), bb, 0, stream>>>(qbf, kbf, vbf, wtq, wtk, wtv, bq,
                                              bk, bv, qh, kh, vt);
  attn_kernel<<<dim3(64, 64), bb, 0, stream>>>(qh, kh, vt, mpack, attn, ctx);
  wo_gemm<<<dim3(64, 8), bb, 0, stream>>>(ctx, wto, bo, out);
}

// Round 9
// 495.155 us; speedup vs baseline: 1.1916x; 1.1916x over previous
//
#include <hip/hip_runtime.h>
#include <hip/hip_bf16.h>

#define B_ 4
#define S_ 2048
#define D_ 1024
#define H_ 16
#define TSZ 8388608L  // B*S*D elements

typedef short short8 __attribute__((ext_vector_type(8)));
typedef float f32x4 __attribute__((ext_vector_type(4)));

__device__ inline unsigned short f2b(float f) {
  __hip_bfloat16 h = __float2bfloat16(f);
  return __builtin_bit_cast(unsigned short, h);
}
// async global->LDS, 16 bytes per lane; LDS dest must be wave-uniform base
__device__ inline void gld16(const unsigned short* g, unsigned short* l) {
  __builtin_amdgcn_global_load_lds(
      (const __attribute__((address_space(1))) void*)g,
      (__attribute__((address_space(3))) void*)l, 16, 0, 0);
}

// ---------------- mask pack: int32 (B,S,S) -> bitmask ----------------------
// word index = ((row*16 + kt)*4 + g), bit (nb*4+r) = mask[row][kt*128+nb*16+g*4+r]
__global__ __launch_bounds__(256) void mask_pack(const int* __restrict__ mask,
                                                 unsigned int* __restrict__ mp) {
  long t = (long)blockIdx.x * 256 + threadIdx.x;  // t = row*16 + kt
  const int4* p = (const int4*)(mask + (t >> 4) * (long)S_ + (t & 15) * 128);
  unsigned int w0 = 0, w1 = 0, w2 = 0, w3 = 0;
#pragma unroll
  for (int c = 0; c < 32; c++) {
    int4 v = p[c];
#pragma unroll
    for (int e = 0; e < 4; e++) {
      int k = c * 4 + e;
      int val = e == 0 ? v.x : e == 1 ? v.y : e == 2 ? v.z : v.w;
      int nb = k >> 4, p16 = k & 15;
      int gg = p16 >> 2, r = p16 & 3;
      unsigned bit = ((unsigned)val & 1u) << (nb * 4 + r);
      if (gg == 0) w0 |= bit; else if (gg == 1) w1 |= bit;
      else if (gg == 2) w2 |= bit; else w3 |= bit;
    }
  }
  *(uint4*)(mp + t * 4) = make_uint4(w0, w1, w2, w3);
}

// ---------------- f32 -> bf16 convert for Q,K,V (one launch) ---------------
__global__ __launch_bounds__(256) void cvt3(
    const float* __restrict__ Q, const float* __restrict__ K,
    const float* __restrict__ V, unsigned short* __restrict__ qo,
    unsigned short* __restrict__ ko, unsigned short* __restrict__ vo) {
  int seg = blockIdx.x >> 12;
  long i = ((long)(blockIdx.x & 4095) * 256 + threadIdx.x) * 8;
  const float* in = seg == 0 ? Q : seg == 1 ? K : V;
  unsigned short* out = seg == 0 ? qo : seg == 1 ? ko : vo;
  float4 a = *(const float4*)(in + i);
  float4 b = *(const float4*)(in + i + 4);
  short8 u;
  u[0] = (short)f2b(a.x); u[1] = (short)f2b(a.y);
  u[2] = (short)f2b(a.z); u[3] = (short)f2b(a.w);
  u[4] = (short)f2b(b.x); u[5] = (short)f2b(b.y);
  u[6] = (short)f2b(b.z); u[7] = (short)f2b(b.w);
  *(short8*)(out + i) = u;
}

// ---------------- weight transpose x4: W f32 [K][N] -> Wt bf16 [N][K] ------
__global__ __launch_bounds__(256) void transpose_w4(
    const float* __restrict__ W0, const float* __restrict__ W1,
    const float* __restrict__ W2, const float* __restrict__ W3,
    unsigned short* __restrict__ T0, unsigned short* __restrict__ T1,
    unsigned short* __restrict__ T2, unsigned short* __restrict__ T3) {
  __shared__ unsigned short t[64 * 72];  // [k][n] pitch 72
  const int z = blockIdx.z;
  const float* W = z == 0 ? W0 : z == 1 ? W1 : z == 2 ? W2 : W3;
  unsigned short* Wt = z == 0 ? T0 : z == 1 ? T1 : z == 2 ? T2 : T3;
  const int tid = threadIdx.x;
  const int k0 = blockIdx.x * 64, n0 = blockIdx.y * 64;
#pragma unroll
  for (int p = 0; p < 4; p++) {
    int e = (p * 256 + tid) * 4;
    int r = e >> 6, c = e & 63;
    float4 v = *(const float4*)(W + (long)(k0 + r) * D_ + n0 + c);
    ushort4 u;
    u.x = f2b(v.x); u.y = f2b(v.y); u.z = f2b(v.z); u.w = f2b(v.w);
    *(ushort4*)(&t[r * 72 + c]) = u;
  }
  __syncthreads();
#pragma unroll
  for (int p = 0; p < 2; p++) {
    int e = (p * 256 + tid) * 8;
    int n = e >> 6, kc = e & 63;
    short8 x;
#pragma unroll
    for (int i = 0; i < 8; i++) x[i] = (short)t[(kc + i) * 72 + n];
    *(short8*)(Wt + (long)(n0 + n) * D_ + k0 + kc) = x;
  }
}

// ---------------- fused QKV projection GEMM --------------------------------
// z=0: Q->qh (head-major), z=1: K->kh (head-major), z=2: V->vt (transposed,
// sigma-permuted within 32-key chunks + row-XOR swizzle for attn LDS)
__global__ __launch_bounds__(256) void qkv_gemm(
    const unsigned short* __restrict__ qa, const unsigned short* __restrict__ ka,
    const unsigned short* __restrict__ va, const unsigned short* __restrict__ wq,
    const unsigned short* __restrict__ wk, const unsigned short* __restrict__ wv,
    const float* __restrict__ bqp, const float* __restrict__ bkp,
    const float* __restrict__ bvp, unsigned short* __restrict__ qo,
    unsigned short* __restrict__ ko, unsigned short* __restrict__ vo) {
  __shared__ unsigned short Asm[128 * 32];
  __shared__ unsigned short Bsm[128 * 32];
  const int z = blockIdx.z;
  const unsigned short* A = z == 0 ? qa : z == 1 ? ka : va;
  const unsigned short* Wt = z == 0 ? wq : z == 1 ? wk : wv;
  const float* bias = z == 0 ? bqp : z == 1 ? bkp : bvp;
  unsigned short* outp = z == 0 ? qo : z == 1 ? ko : vo;
  const int tid = threadIdx.x;
  const int lane = tid & 63, wid = tid >> 6;
  const int g = lane >> 4, li = lane & 15;
  const int wm = wid >> 1, wn = wid & 1;
  const long bm = (long)blockIdx.x * 128;
  const long bn = (long)blockIdx.y * 128;

  f32x4 acc[4][4];
#pragma unroll
  for (int i = 0; i < 4; i++)
#pragma unroll
    for (int j = 0; j < 4; j++) acc[i][j] = (f32x4){0.f, 0.f, 0.f, 0.f};

  for (int kt = 0; kt < 32; ++kt) {
    const int k0 = kt * 32;
    __syncthreads();
#pragma unroll
    for (int p = 0; p < 2; p++) {
      int ci = p * 256 + wid * 64 + lane;
      int r = ci >> 2, c = (ci & 3) * 8;
      gld16(A + (bm + r) * 1024L + k0 + c, &Asm[(p * 256 + wid * 64) * 8]);
      gld16(Wt + (bn + r) * 1024L + k0 + c, &Bsm[(p * 256 + wid * 64) * 8]);
    }
    __syncthreads();
    short8 af[4], bf[4];
#pragma unroll
    for (int i = 0; i < 4; i++)
      af[i] = *(const short8*)(&Asm[(wm * 64 + i * 16 + li) * 32 + g * 8]);
#pragma unroll
    for (int i = 0; i < 4; i++)
      bf[i] = *(const short8*)(&Bsm[(wn * 64 + i * 16 + li) * 32 + g * 8]);
#pragma unroll
    for (int i = 0; i < 4; i++)
#pragma unroll
      for (int j = 0; j < 4; j++)
        acc[i][j] =
            __builtin_amdgcn_mfma_f32_16x16x32_bf16(af[i], bf[j], acc[i][j], 0, 0, 0);
  }

#pragma unroll
  for (int i = 0; i < 4; i++) {
    int row0 = (int)bm + wm * 64 + i * 16 + g * 4;
#pragma unroll
    for (int j = 0; j < 4; j++) {
      int col = (int)bn + wn * 64 + j * 16 + li;
      float bvv = bias[col];
      if (z == 2) {
        int b = row0 >> 11, s0 = row0 & 2047;
        int h = col >> 6, dd = col & 63;
        ushort4 u;
#pragma unroll
        for (int jj = 0; jj < 4; jj++) u[jj] = f2b(acc[i][j][jj] + bvv);
        // sigma permute within 32-key chunk, then row-XOR swizzle
        int kh2 = s0 & 31;
        int s1 = (s0 & ~31) | (((kh2 >> 2) & 3) << 3) | (((kh2 >> 4) & 1) << 2);
        int s2 = s1 ^ ((dd & 7) << 3);
        *(ushort4*)(outp + ((long)(b * H_ + h) * 64 + dd) * S_ + s2) = u;
      } else {
#pragma unroll
        for (int jj = 0; jj < 4; jj++) {
          int row = row0 + jj;
          int b = row >> 11, s = row & 2047;
          int h = col >> 6, dd = col & 63;
          outp[(((long)(b * H_ + h)) * S_ + s) * 64 + dd] =
              f2b(acc[i][j][jj] + bvv);
        }
      }
    }
  }
}

// ---------------- output GEMM: out = ctx @ Wo^T + bo (f32 out) -------------
__global__ __launch_bounds__(256) void wo_gemm(
    const unsigned short* __restrict__ A, const unsigned short* __restrict__ Wt,
    const float* __restrict__ bias, float* __restrict__ out) {
  __shared__ unsigned short Asm[128 * 32];
  __shared__ unsigned short Bsm[128 * 32];
  const int tid = threadIdx.x;
  const int lane = tid & 63, wid = tid >> 6;
  const int g = lane >> 4, li = lane & 15;
  const int wm = wid >> 1, wn = wid & 1;
  const long bm = (long)blockIdx.x * 128;
  const long bn = (long)blockIdx.y * 128;

  f32x4 acc[4][4];
#pragma unroll
  for (int i = 0; i < 4; i++)
#pragma unroll
    for (int j = 0; j < 4; j++) acc[i][j] = (f32x4){0.f, 0.f, 0.f, 0.f};

  for (int kt = 0; kt < 32; ++kt) {
    const int k0 = kt * 32;
    __syncthreads();
#pragma unroll
    for (int p = 0; p < 2; p++) {
      int ci = p * 256 + wid * 64 + lane;
      int r = ci >> 2, c = (ci & 3) * 8;
      gld16(A + (bm + r) * 1024L + k0 + c, &Asm[(p * 256 + wid * 64) * 8]);
      gld16(Wt + (bn + r) * 1024L + k0 + c, &Bsm[(p * 256 + wid * 64) * 8]);
    }
    __syncthreads();
    short8 af[4], bf[4];
#pragma unroll
    for (int i = 0; i < 4; i++)
      af[i] = *(const short8*)(&Asm[(wm * 64 + i * 16 + li) * 32 + g * 8]);
#pragma unroll
    for (int i = 0; i < 4; i++)
      bf[i] = *(const short8*)(&Bsm[(wn * 64 + i * 16 + li) * 32 + g * 8]);
#pragma unroll
    for (int i = 0; i < 4; i++)
#pragma unroll
      for (int j = 0; j < 4; j++)
        acc[i][j] =
            __builtin_amdgcn_mfma_f32_16x16x32_bf16(af[i], bf[j], acc[i][j], 0, 0, 0);
  }

#pragma unroll
  for (int i = 0; i < 4; i++) {
    int row0 = (int)bm + wm * 64 + i * 16 + g * 4;
#pragma unroll
    for (int j = 0; j < 4; j++) {
      int col = (int)bn + wn * 64 + j * 16 + li;
      float bvv = bias[col];
#pragma unroll
      for (int jj = 0; jj < 4; jj++)
        out[(long)(row0 + jj) * 1024 + col] = acc[i][j][jj] + bvv;
    }
  }
}

// ---------------- fused attn: q-split, 32 q-rows/wave, V via gld16 ---------
__global__ __launch_bounds__(256, 3) void attn_kernel(
    const unsigned short* __restrict__ q,    // (BH,S,64)
    const unsigned short* __restrict__ k,    // (BH,S,64) plain
    const unsigned short* __restrict__ vt,   // (BH,64,S) sigma+XOR swizzled
    const unsigned int* __restrict__ mpk,    // packed mask
    float* __restrict__ attn,                // (BH,S,S) f32
    unsigned short* __restrict__ ctx) {      // (B,S,D) bf16
  __shared__ unsigned short k_lds[128 * 72];  // [key][dd] pitch 72
  __shared__ unsigned short v_lds[64 * 128];  // linear, swizzle baked in source
  const int tid = threadIdx.x;
  const int lane = tid & 63, w = tid >> 6;
  const int g = lane >> 4, li = lane & 15;
  // XCD-cluster swizzle (bijective): 8 heads per XCD, 16 blocks/head
  const int p0 = blockIdx.x + 16 * blockIdx.y;
  const int xcd = p0 & 7, q8 = p0 >> 3;
  const int bx = q8 & 15, bh = xcd * 8 + (q8 >> 4);
  const int b = bh >> 4, h = bh & 15;
  const int qw = bx * 128 + w * 32;  // this wave's 32 q-rows

  const unsigned short* qp = q + ((long)bh * S_ + qw) * 64;
  short8 aq0[2], aq1[2];
#pragma unroll
  for (int qb = 0; qb < 2; qb++) {
    aq0[qb] = *(const short8*)(qp + (qb * 16 + li) * 64 + g * 8);
    aq1[qb] = *(const short8*)(qp + (qb * 16 + li) * 64 + 32 + g * 8);
  }
  const unsigned int* mpb0 = mpk + ((long)(b * S_ + qw + li) * 16) * 4 + g;
  const unsigned int* mpb1 = mpb0 + 1024;  // +16 rows

  const unsigned short* kbase = k + (long)bh * S_ * 64;
  const unsigned short* vbase = vt + (long)bh * 64 * S_;
  int kst[4], kgo[4], vsrc[4];
#pragma unroll
  for (int p = 0; p < 4; p++) {
    int e = (p * 256 + tid) * 8;
    int kr = e >> 6, kc = e & 63;  // K tile 128x64
    kst[p] = kr * 72 + kc;
    kgo[p] = kr * 64 + kc;
    int ci = p * 256 + tid;        // V tile 64x128
    vsrc[p] = (ci >> 4) * S_ + (ci & 15) * 8;
  }

  // ---- pass 1: denominators (K in LDS, reg ping-pong prefetch) ----
  float ls0 = 0.f, ls1 = 0.f;
  short8 kreg[4];
#pragma unroll
  for (int p = 0; p < 4; p++) kreg[p] = *(const short8*)(kbase + kgo[p]);
  unsigned int mA0 = mpb0[0], mA1 = mpb1[0];
  for (int kt = 0; kt < 16; ++kt) {
    __syncthreads();
#pragma unroll
    for (int p = 0; p < 4; p++) *(short8*)(&k_lds[kst[p]]) = kreg[p];
    unsigned int mb0 = mA0, mb1 = mA1;
    if (kt < 15) {
#pragma unroll
      for (int p = 0; p < 4; p++)
        kreg[p] = *(const short8*)(kbase + (kt + 1) * 8192 + kgo[p]);
      mA0 = mpb0[(kt + 1) * 4];
      mA1 = mpb1[(kt + 1) * 4];
    }
    __syncthreads();
#pragma unroll
    for (int nb = 0; nb < 8; nb++) {
      short8 b0 = *(const short8*)(&k_lds[(nb * 16 + li) * 72 + g * 8]);
      short8 b1 = *(const short8*)(&k_lds[(nb * 16 + li) * 72 + 32 + g * 8]);
      f32x4 s0 = (f32x4){0.f, 0.f, 0.f, 0.f};
      f32x4 s1 = (f32x4){0.f, 0.f, 0.f, 0.f};
      __builtin_amdgcn_s_setprio(1);
      s0 = __builtin_amdgcn_mfma_f32_16x16x32_bf16(b0, aq0[0], s0, 0, 0, 0);
      s0 = __builtin_amdgcn_mfma_f32_16x16x32_bf16(b1, aq1[0], s0, 0, 0, 0);
      s1 = __builtin_amdgcn_mfma_f32_16x16x32_bf16(b0, aq0[1], s1, 0, 0, 0);
      s1 = __builtin_amdgcn_mfma_f32_16x16x32_bf16(b1, aq1[1], s1, 0, 0, 0);
      __builtin_amdgcn_s_setprio(0);
#pragma unroll
      for (int r = 0; r < 4; r++) {
        int bi = nb * 4 + r;
        ls0 += __expf(s0[r] * 0.125f + (((mb0 >> bi) & 1u) ? 0.f : -1e9f));
        ls1 += __expf(s1[r] * 0.125f + (((mb1 >> bi) & 1u) ? 0.f : -1e9f));
      }
    }
  }
  ls0 += __shfl_xor(ls0, 16); ls0 += __shfl_xor(ls0, 32);
  ls1 += __shfl_xor(ls1, 16); ls1 += __shfl_xor(ls1, 32);
  const float linv0 = (ls0 > 0.f) ? 1.0f / ls0 : 0.f;
  const float linv1 = (ls1 > 0.f) ? 1.0f / ls1 : 0.f;

  // ---- pass 2: probs + PV (K reg-staged, V gld16-staged) ----
  f32x4 c[2][4];
#pragma unroll
  for (int qb = 0; qb < 2; qb++)
#pragma unroll
    for (int d = 0; d < 4; d++) c[qb][d] = (f32x4){0.f, 0.f, 0.f, 0.f};
#pragma unroll
  for (int p = 0; p < 4; p++) kreg[p] = *(const short8*)(kbase + kgo[p]);
  mA0 = mpb0[0]; mA1 = mpb1[0];
  float* arow0 = attn + ((long)bh * S_ + qw + li) * S_;
  for (int kt = 0; kt < 16; ++kt) {
    __syncthreads();
#pragma unroll
    for (int p = 0; p < 4; p++) {
      *(short8*)(&k_lds[kst[p]]) = kreg[p];
      gld16(vbase + kt * 128 + vsrc[p], &v_lds[(p * 256 + w * 64) * 8]);
    }
    unsigned int mb0 = mA0, mb1 = mA1;
    if (kt < 15) {
#pragma unroll
      for (int p = 0; p < 4; p++)
        kreg[p] = *(const short8*)(kbase + (kt + 1) * 8192 + kgo[p]);
      mA0 = mpb0[(kt + 1) * 4];
      mA1 = mpb1[(kt + 1) * 4];
    }
    __syncthreads();  // drains gld16 (vmcnt) -> v_lds ready
    short8 pu2[2][4];
#pragma unroll
    for (int nb = 0; nb < 8; nb++) {
      short8 b0 = *(const short8*)(&k_lds[(nb * 16 + li) * 72 + g * 8]);
      short8 b1 = *(const short8*)(&k_lds[(nb * 16 + li) * 72 + 32 + g * 8]);
      f32x4 s0 = (f32x4){0.f, 0.f, 0.f, 0.f};
      f32x4 s1 = (f32x4){0.f, 0.f, 0.f, 0.f};
      __builtin_amdgcn_s_setprio(1);
      s0 = __builtin_amdgcn_mfma_f32_16x16x32_bf16(b0, aq0[0], s0, 0, 0, 0);
      s0 = __builtin_amdgcn_mfma_f32_16x16x32_bf16(b1, aq1[0], s0, 0, 0, 0);
      s1 = __builtin_amdgcn_mfma_f32_16x16x32_bf16(b0, aq0[1], s1, 0, 0, 0);
      s1 = __builtin_amdgcn_mfma_f32_16x16x32_bf16(b1, aq1[1], s1, 0, 0, 0);
      __builtin_amdgcn_s_setprio(0);
      f32x4 pf0, pf1;
      ushort4 pu0, pu1;
#pragma unroll
      for (int r = 0; r < 4; r++) {
        int bi = nb * 4 + r;
        float p0f = __expf(s0[r] * 0.125f + (((mb0 >> bi) & 1u) ? 0.f : -1e9f)) * linv0;
        float p1f = __expf(s1[r] * 0.125f + (((mb1 >> bi) & 1u) ? 0.f : -1e9f)) * linv1;
        pf0[r] = p0f; pu0[r] = f2b(p0f);
        pf1[r] = p1f; pu1[r] = f2b(p1f);
      }
      long acol = kt * 128 + nb * 16 + g * 4;
      __builtin_nontemporal_store(pf0, (f32x4*)(arow0 + acol));
      __builtin_nontemporal_store(pf1, (f32x4*)(arow0 + 16 * S_ + acol));
      ((ushort4*)&pu2[0][nb >> 1])[nb & 1] = pu0;
      ((ushort4*)&pu2[1][nb >> 1])[nb & 1] = pu1;
    }
    __builtin_amdgcn_s_setprio(1);
#pragma unroll
    for (int kc = 0; kc < 4; kc++) {
#pragma unroll
      for (int d = 0; d < 4; d++) {
        short8 bv = *(const short8*)(&v_lds[(d * 16 + li) * 128 +
                                            ((kc * 32 + g * 8) ^ ((li & 7) << 3))]);
        c[0][d] = __builtin_amdgcn_mfma_f32_16x16x32_bf16(pu2[0][kc], bv, c[0][d], 0, 0, 0);
        c[1][d] = __builtin_amdgcn_mfma_f32_16x16x32_bf16(pu2[1][kc], bv, c[1][d], 0, 0, 0);
      }
    }
    __builtin_amdgcn_s_setprio(0);
  }

#pragma unroll
  for (int qb = 0; qb < 2; qb++)
#pragma unroll
    for (int d = 0; d < 4; d++)
#pragma unroll
      for (int jj = 0; jj < 4; jj++) {
        int qrow = qw + qb * 16 + g * 4 + jj;
        ctx[((long)(b * S_ + qrow)) * D_ + h * 64 + d * 16 + li] =
            f2b(c[qb][d][jj]);
      }
}

extern "C" void kernel_launch(void* const* d_in, const int* in_sizes, int n_in,
                              void* d_out, int out_size, void* d_ws, size_t ws_size,
                              hipStream_t stream) {
  const float* Q = (const float*)d_in[0];
  const float* K = (const float*)d_in[1];
  const float* V = (const float*)d_in[2];
  const int* mask = (const int*)d_in[3];
  const float* Wq = (const float*)d_in[4];
  const float* bq = (const float*)d_in[5];
  const float* Wk = (const float*)d_in[6];
  const float* bk = (const float*)d_in[7];
  const float* Wv = (const float*)d_in[8];
  const float* bv = (const float*)d_in[9];
  const float* Wo = (const float*)d_in[10];
  const float* bo = (const float*)d_in[11];

  float* out = (float*)d_out;  // (B,S,D) f32
  float* attn = out + TSZ;     // (B,H,S,S) f32
  // packed mask (2 MB) lives in the out region; overwritten by final GEMM
  unsigned int* mpack = (unsigned int*)d_out;

  unsigned short* ws = (unsigned short*)d_ws;
  unsigned short* qh = ws;              // (BH,S,64) bf16
  unsigned short* kh = ws + TSZ;        // (BH,S,64)
  unsigned short* vt = ws + 2 * TSZ;    // (BH,64,S) swizzled
  unsigned short* ctx = ws + 3 * TSZ;   // (B,S,D) bf16
  unsigned short* qbf = ws + 4 * TSZ;   // bf16 inputs
  unsigned short* kbf = ws + 5 * TSZ;
  unsigned short* vbf = ws + 6 * TSZ;
  unsigned short* wtq = ws + 7 * TSZ;
  unsigned short* wtk = wtq + 1048576;
  unsigned short* wtv = wtk + 1048576;
  unsigned short* wto = wtv + 1048576;

  dim3 bb(256);
  mask_pack<<<512, bb, 0, stream>>>(mask, mpack);
  cvt3<<<12288, bb, 0, stream>>>(Q, K, V, qbf, kbf, vbf);
  transpose_w4<<<dim3(16, 16, 4), bb, 0, stream>>>(Wq, Wk, Wv, Wo, wtq, wtk,
                                                   wtv, wto);
  qkv_gemm<<<dim3(64, 8, 3), bb, 0, stream>>>(qbf, kbf, vbf, wtq, wtk, wtv, bq,
                                              bk, bv, qh, kh, vt);
  attn_kernel<<<dim3(16, 64), bb, 0, stream>>>(qh, kh, vt, mpack, attn, ctx);
  wo_gemm<<<dim3(64, 8), bb, 0, stream>>>(ctx, wto, bo, out);
}